// Round 5
// baseline (135.728 us; speedup 1.0000x reference)
//
#include <hip/hip_runtime.h>
#include <math.h>

#define B_ 8
#define N_ 16384
#define M_ 128
#define C_ 81
#define TPB 512
#define KPT 32              // keys per thread = N_/TPB
#define NWAVE (TPB / 64)    // 8

// ============ Kernel A: GT hbb (LDS float4) + IoU + argmax, 2 preds/thread ====
__global__ __launch_bounds__(256)
void iou_fused(const float* __restrict__ bp,     // [B,N,5]
               const float* __restrict__ rt,     // [B,M,4,2]
               float* __restrict__ miou,         // [B,N]
               int* __restrict__ match,          // [B,N]
               float* __restrict__ out) {        // [3] zeroed here
    __shared__ float4 sbox[M_];
    int b = blockIdx.y;
    int tid = threadIdx.x;

    if (blockIdx.x == 0 && b == 0 && tid < 3) out[tid] = 0.0f;

    if (tid < M_) {
        const float* v = rt + ((size_t)b * M_ + tid) * 8;
        float x0 = v[0], y0 = v[1], x1 = v[2], y1 = v[3];
        float x2 = v[4], y2 = v[5], x3 = v[6], y3 = v[7];
        float mnx = fminf(fminf(x0, x1), fminf(x2, x3));
        float mny = fminf(fminf(y0, y1), fminf(y2, y3));
        float mxx = fmaxf(fmaxf(x0, x1), fmaxf(x2, x3));
        float mxy = fmaxf(fmaxf(y0, y1), fmaxf(y2, y3));
        sbox[tid] = make_float4(mnx, mny, mxx, mxy);
    }
    __syncthreads();

    int p0 = blockIdx.x * 512 + tid;           // preds p0 and p0+256
    float ax1[2], ay1[2], ax2[2], ay2[2], aa[2];
#pragma unroll
    for (int t = 0; t < 2; t++) {
        const float* p = bp + ((size_t)b * N_ + p0 + 256 * t) * 5;
        float cx = p[0], cy = p[1], w = p[2], h = p[3], a = p[4];
        float c = cosf(a), s = sinf(a);
        float dx = w * 0.5f, dy = h * 0.5f;
        float ex = fabsf(dx * c) + fabsf(dy * s);
        float ey = fabsf(dx * s) + fabsf(dy * c);
        ax1[t] = cx - ex; ay1[t] = cy - ey; ax2[t] = cx + ex; ay2[t] = cy + ey;
        aa[t] = (ax2[t] - ax1[t]) * (ay2[t] - ay1[t]);
    }
    float bin[2] = {-1.f, -1.f}, bun[2] = {1.f, 1.f};
    int bm[2] = {0, 0};
#pragma unroll 2
    for (int m = 0; m < M_; m++) {
        float4 bb = sbox[m];
        float ab = (bb.z - bb.x) * (bb.w - bb.y);
#pragma unroll
        for (int t = 0; t < 2; t++) {
            float lx = fmaxf(ax1[t], bb.x), ly = fmaxf(ay1[t], bb.y);
            float rx = fminf(ax2[t], bb.z), ry = fminf(ay2[t], bb.w);
            float ww = fmaxf(rx - lx, 0.0f), hh = fmaxf(ry - ly, 0.0f);
            float inter = ww * hh;
            float uni = fmaxf(aa[t] + ab - inter, 1e-7f);
            bool better = inter * bun[t] > bin[t] * uni;  // iou_m > best
            bin[t] = better ? inter : bin[t];
            bun[t] = better ? uni : bun[t];
            bm[t] = better ? m : bm[t];
        }
    }
#pragma unroll
    for (int t = 0; t < 2; t++) {
        miou[(size_t)b * N_ + p0 + 256 * t] = bin[t] / bun[t];
        match[(size_t)b * N_ + p0 + 256 * t] = bm[t];
    }
}

// ============ ballot helpers ============
__device__ __forceinline__ unsigned wsum6(unsigned c) {        // c <= 63
    unsigned s = 0;
#pragma unroll
    for (int bit = 0; bit < 6; bit++)
        s += (unsigned)__popcll(__ballot((c >> bit) & 1u)) << bit;
    return s;
}
__device__ __forceinline__ unsigned wprefix6(unsigned c, unsigned long long lt) {
    unsigned s = 0;                                            // exclusive, c <= 63
#pragma unroll
    for (int bit = 0; bit < 6; bit++)
        s += (unsigned)__popcll(__ballot((c >> bit) & 1u) & lt) << bit;
    return s;
}
__device__ __forceinline__ unsigned wsum2(unsigned c) {        // c <= 2
    return (unsigned)__popcll(__ballot(c & 1u)) +
           ((unsigned)__popcll(__ballot((c >> 1) & 1u)) << 1);
}
__device__ __forceinline__ unsigned bsum6(unsigned c, unsigned* slot) {
    unsigned ws = wsum6(c);
    if ((threadIdx.x & 63) == 0) slot[threadIdx.x >> 6] = ws;
    __syncthreads();
    unsigned r = 0;
#pragma unroll
    for (int i = 0; i < NWAVE; i++) r += slot[i];
    return r;
}
__device__ __forceinline__ unsigned bsum2(unsigned c, unsigned* slot) {
    unsigned ws = wsum2(c);
    if ((threadIdx.x & 63) == 0) slot[threadIdx.x >> 6] = ws;
    __syncthreads();
    unsigned r = 0;
#pragma unroll
    for (int i = 0; i < NWAVE; i++) r += slot[i];
    return r;
}

// ============ Kernel B: hierarchical exact top-k + loss ============
// blockIdx.x: 0 = positives (iou desc, idx asc), 1 = negatives (iou asc, idx asc)
__global__ __launch_bounds__(TPB)
void select_loss(const float* __restrict__ miou, const int* __restrict__ match,
                 const float* __restrict__ logits, const float* __restrict__ bp,
                 const float* __restrict__ rt, const int* __restrict__ labels,
                 const int* __restrict__ ns_ptr, float* __restrict__ out) {
    int type = blockIdx.x;
    int b = blockIdx.y;
    __shared__ float s_cv2[5][M_];
    __shared__ unsigned red[2 * NWAVE] __attribute__((aligned(16)));
    __shared__ float fredc[NWAVE], fredr[NWAVE];
    __shared__ unsigned cand_key[NWAVE * 128];
    __shared__ unsigned cand_idx[NWAVE * 128];
    __shared__ unsigned sel[256];
    __shared__ unsigned selcnt;

    int tid = threadIdx.x;
    int lane = tid & 63, wv = tid >> 6;
    unsigned long long ltmask = ((unsigned long long)1 << lane) - 1ull;
    if (tid == 0) selcnt = 0;

    if (tid < M_) {
        const float* v = rt + ((size_t)b * M_ + tid) * 8;
        float x0 = v[0], y0 = v[1], x1 = v[2], y1 = v[3];
        float x2 = v[4], y2 = v[5], x3 = v[6], y3 = v[7];
        s_cv2[0][tid] = (x0 + x1 + x2 + x3) * 0.25f;
        s_cv2[1][tid] = (y0 + y1 + y2 + y3) * 0.25f;
        float e1x = x1 - x0, e1y = y1 - y0;
        float e2x = x3 - x0, e2y = y3 - y0;
        s_cv2[2][tid] = sqrtf(e1x * e1x + e1y * e1y);
        s_cv2[3][tid] = sqrtf(e2x * e2x + e2y * e2y);
        s_cv2[4][tid] = atan2f(e1y, e1x);
    }

    int ns = ns_ptr[0];
    unsigned ktar = (type == 0) ? (unsigned)(ns / 2) : (unsigned)(ns - ns / 2);
    if (ktar > 256u) ktar = 256u;

    // ---- load KPT ious, build order keys (sentinel 0xFFFFFFFF = invalid) ----
    const float4* mi4 = (const float4*)(miou + (size_t)b * N_);
    int base = tid * KPT;
    unsigned key[KPT];
    unsigned vcnt = 0;
#pragma unroll
    for (int q = 0; q < KPT / 4; q++) {
        float4 v4 = mi4[tid * (KPT / 4) + q];
        float io[4] = {v4.x, v4.y, v4.z, v4.w};
#pragma unroll
        for (int j = 0; j < 4; j++) {
            bool pos = (io[j] >= 0.5f);
            unsigned k;
            if (type == 0) {
                if (pos) { k = ~(__float_as_uint(io[j]) | 0x80000000u); vcnt++; }
                else k = 0xFFFFFFFFu;
            } else {
                if (!pos) { k = __float_as_uint(io[j]) | 0x80000000u; vcnt++; }
                else k = 0xFFFFFFFFu;
            }
            key[q * 4 + j] = k;
        }
    }
    __syncthreads();  // selcnt + s_cv2 visible

    int pc = 0;
    unsigned V = bsum6(vcnt, red + NWAVE * ((pc++) & 1));
    unsigned keff = (ktar < V) ? ktar : V;

    if (keff == V) {
        // fast path: every valid item selected (order irrelevant — sum)
#pragma unroll
        for (int j = 0; j < KPT; j++) {
            if (key[j] != 0xFFFFFFFFu) {
                unsigned p = atomicAdd(&selcnt, 1u);
                sel[p] = (unsigned)(base + j);
            }
        }
    } else {
        // ===== Phase 1: per-wave local top-128 candidates (ballot-only) =====
        unsigned Vw = wsum6(vcnt);
        unsigned kw = (Vw < 128u) ? Vw : 128u;
        unsigned wbase = wv * 128u;
        if (kw > 0) {
            // search range by key structure: positives keys in [0x40000000,0x41000000),
            // negatives keys in [0x80000000, 0xBF000000]
            unsigned lo = (type == 0) ? 0x40000000u : 0x80000000u;
            unsigned hi = (type == 0) ? 0x41000000u : 0xBF000000u;
            if (type == 1) {  // probe: many exact-zero ious?
                unsigned c = 0;
#pragma unroll
                for (int j = 0; j < KPT; j++) c += (key[j] <= 0x80000000u) ? 1u : 0u;
                if (wsum6(c) >= kw) { lo = hi = 0x80000000u; }
            }
            while (lo < hi) {
                unsigned mid = lo + ((hi - lo) >> 1);
                unsigned c = 0;
#pragma unroll
                for (int j = 0; j < KPT; j++) c += (key[j] <= mid) ? 1u : 0u;
                if (wsum6(c) >= kw) hi = mid; else lo = mid + 1;
            }
            unsigned cutW = lo;
            unsigned clw = 0, cew = 0;
#pragma unroll
            for (int j = 0; j < KPT; j++) {
                clw += (key[j] < cutW) ? 1u : 0u;
                cew += (key[j] == cutW) ? 1u : 0u;
            }
            unsigned mw = wsum6(clw);
            unsigned ew = kw - mw;                       // wave ties kept (by idx)
            unsigned r = wprefix6(cew, ltmask);          // ties in lower lanes
            unsigned selc = 0;
            unsigned selMask = 0;
#pragma unroll
            for (int j = 0; j < KPT; j++) {
                bool tie = (key[j] == cutW);
                bool s = (key[j] < cutW) || (tie && r < ew);
                if (tie) r++;
                if (s) { selMask |= (1u << j); selc++; }
            }
            unsigned woff = wprefix6(selc, ltmask);      // compaction offset
#pragma unroll
            for (int j = 0; j < KPT; j++) {
                if ((selMask >> j) & 1u) {
                    cand_key[wbase + woff] = key[j];
                    cand_idx[wbase + woff] = (unsigned)(base + j);
                    woff++;
                }
            }
        }
        // pad wave region [kw,128) with sentinels
        for (unsigned p = kw + (unsigned)lane; p < 128u; p += 64u) {
            cand_key[wbase + p] = 0xFFFFFFFFu;
            cand_idx[wbase + p] = 0u;
        }
        __syncthreads();

        // ===== Phase 2: block search over <=1024 candidates (2/thread) =====
        unsigned ck0 = cand_key[tid], ck1 = cand_key[tid + TPB];
        unsigned ci0 = cand_idx[tid], ci1 = cand_idx[tid + TPB];
        unsigned lo = (type == 0) ? 0x40000000u : 0x80000000u;
        unsigned hi = (type == 0) ? 0x41000000u : 0xBF000000u;
        while (lo < hi) {
            unsigned mid = lo + ((hi - lo) >> 1);
            unsigned c = ((ck0 <= mid) ? 1u : 0u) + ((ck1 <= mid) ? 1u : 0u);
            unsigned tot = bsum2(c, red + NWAVE * ((pc++) & 1));
            if (tot >= keff) hi = mid; else lo = mid + 1;
        }
        unsigned Ckey = lo;
        unsigned c2 = ((ck0 < Ckey) ? 1u : 0u) + ((ck1 < Ckey) ? 1u : 0u);
        unsigned m = bsum2(c2, red + NWAVE * ((pc++) & 1));
        unsigned e = keff - m;                            // ties to take by idx
        unsigned X = 0xFFFFFFFFu;                         // idx cutoff
        if (e > 0) {
            unsigned ilo = 0, ihi = N_ - 1;
            while (ilo < ihi) {
                unsigned mid = ilo + ((ihi - ilo) >> 1);
                unsigned c = ((ck0 == Ckey && ci0 <= mid) ? 1u : 0u) +
                             ((ck1 == Ckey && ci1 <= mid) ? 1u : 0u);
                unsigned tot = bsum2(c, red + NWAVE * ((pc++) & 1));
                if (tot >= e) ihi = mid; else ilo = mid + 1;
            }
            X = ilo;
        }
        // select from candidate slots (idx unique -> exact count)
        if ((ck0 < Ckey) || (ck0 == Ckey && e > 0 && ci0 <= X)) {
            unsigned p = atomicAdd(&selcnt, 1u); sel[p] = ci0;
        }
        if ((ck1 < Ckey) || (ck1 == Ckey && e > 0 && ci1 <= X)) {
            unsigned p = atomicAdd(&selcnt, 1u); sel[p] = ci1;
        }
    }
    __syncthreads();
    unsigned total_sel = selcnt;  // == keff

    // ---- loss: 4 threads per sample, 21 logits each ----
    float cls_sum = 0.f, reg_sum = 0.f;
    int q = tid & 3;
    for (unsigned sm = (unsigned)(tid >> 2); sm < total_sel; sm += TPB / 4) {
        unsigned i = sel[sm];
        const float* row = logits + ((size_t)b * N_ + i) * C_;
        int c0 = q * 21;
        int c1 = (c0 + 21 < C_) ? c0 + 21 : C_;
        float mx = -INFINITY;
        for (int c = c0; c < c1; c++) mx = fmaxf(mx, row[c]);
        mx = fmaxf(mx, __shfl_xor(mx, 1));
        mx = fmaxf(mx, __shfl_xor(mx, 2));
        float se = 0.f;
        for (int c = c0; c < c1; c++) se += expf(row[c] - mx);
        se += __shfl_xor(se, 1);
        se += __shfl_xor(se, 2);
        if (q == 0) {
            float lse = mx + logf(se);
            if (type == 0) {
                int g_gt = match[(size_t)b * N_ + i];
                int tc = labels[b * M_ + g_gt];
                cls_sum += lse - row[tc];
                const float* pp = bp + ((size_t)b * N_ + i) * 5;
#pragma unroll
                for (int d = 0; d < 5; d++) {
                    float ad = fabsf(pp[d] - s_cv2[d][g_gt]);
                    reg_sum += (ad < 1.f) ? 0.5f * ad * ad : ad - 0.5f;
                }
            } else {
                cls_sum += lse - row[C_ - 1];
            }
        }
    }

    // ---- final reduce + atomic out ----
#pragma unroll
    for (int o = 32; o; o >>= 1) {
        cls_sum += __shfl_down(cls_sum, o);
        reg_sum += __shfl_down(reg_sum, o);
    }
    if (lane == 0) { fredc[wv] = cls_sum; fredr[wv] = reg_sum; }
    __syncthreads();
    if (tid == 0) {
        float cs = 0.f, rs = 0.f;
#pragma unroll
        for (int i = 0; i < NWAVE; i++) { cs += fredc[i]; rs += fredr[i]; }
        const float invB = 1.0f / (float)B_;
        atomicAdd(&out[0], (cs + rs) * invB);
        atomicAdd(&out[1], cs * invB);
        atomicAdd(&out[2], rs * invB);
    }
}

extern "C" void kernel_launch(void* const* d_in, const int* in_sizes, int n_in,
                              void* d_out, int out_size, void* d_ws, size_t ws_size,
                              hipStream_t stream) {
    const float* box_pred = (const float*)d_in[0];     // [B,N,5]
    const float* class_pred = (const float*)d_in[1];   // [B,N,C]
    const float* reg_tgt = (const float*)d_in[2];      // [B,M,4,2]
    const int* cls_tgt = (const int*)d_in[3];          // [B,M]
    const int* n_samples = (const int*)d_in[4];        // [1]

    float* ws = (float*)d_ws;
    float* miou = ws;                                  // B*N (16B aligned)
    int* match = (int*)(miou + (size_t)B_ * N_);       // B*N
    float* out = (float*)d_out;

    iou_fused<<<dim3(N_ / 512, B_), 256, 0, stream>>>(box_pred, reg_tgt, miou, match, out);
    select_loss<<<dim3(2, B_), TPB, 0, stream>>>(miou, match, class_pred, box_pred,
                                                 reg_tgt, cls_tgt, n_samples, out);
}